// Round 1
// baseline (726.951 us; speedup 1.0000x reference)
//
#include <hip/hip_runtime.h>

#define F    8192
#define KD   64     // coordinate dimensionality
#define NB   8      // neighbors
#define TI   16     // rows per workgroup (knn kernel)
#define TJ   256    // cols per LDS tile

// ---------------------------------------------------------------------------
// Kernel 1: squared norms. MUST use the same ascending-k fmaf chain as the
// dot product in knn_kernel so that dot(i,i) == sq[i] bit-exact, which makes
// d2[i][i] == 0 exactly (self is always the first neighbor, matching ref).
// ---------------------------------------------------------------------------
__global__ __launch_bounds__(256) void sq_kernel(const float* __restrict__ crd,
                                                 float* __restrict__ sq) {
    int f = blockIdx.x * 256 + threadIdx.x;
    float acc = 0.f;
    for (int k = 0; k < KD; ++k) {
        float x = crd[k * F + f];
        acc = fmaf(x, x, acc);
    }
    sq[f] = acc;
}

// ---------------------------------------------------------------------------
// Kernel 2: fused distance + top-8.
// Block = 256 threads = 4 waves. ty = wave id (0..3), tx = lane (0..63).
// Each thread: 4 rows (ty*4+r) x 4 cols (tx*4+c) register tile per j-tile.
// Per-thread sorted top-8 per row; merged per row via LDS at the end.
// LDS: A_s 4 KB + B_s 64 KB (B_s reused as the merge buffer).
// ---------------------------------------------------------------------------
__global__ __launch_bounds__(256) void knn_kernel(const float* __restrict__ crd,
                                                  const float* __restrict__ sq,
                                                  int* __restrict__ knn) {
    __shared__ float A_s[KD][TI];   // [k][row_local], 4 KB
    __shared__ float B_s[KD][TJ];   // [k][col_local], 64 KB

    const int tid = threadIdx.x;
    const int ty  = tid >> 6;   // wave id
    const int tx  = tid & 63;   // lane
    const int rowBase = blockIdx.x * TI;

    // stage A tile (once per block)
    for (int l = tid; l < KD * TI; l += 256) {
        int k = l >> 4, il = l & 15;
        A_s[k][il] = crd[k * F + rowBase + il];
    }

    // per-thread top-8 (sorted ascending) for each of this thread's 4 rows
    float tv[4][NB];
    int   tix[4][NB];
#pragma unroll
    for (int r = 0; r < 4; ++r)
#pragma unroll
        for (int s = 0; s < NB; ++s) { tv[r][s] = INFINITY; tix[r][s] = 0x7fffffff; }

    __syncthreads();   // A_s ready

    float sqi[4];
#pragma unroll
    for (int r = 0; r < 4; ++r) sqi[r] = sq[rowBase + ty * 4 + r];

    const float4* crd4 = (const float4*)crd;

    for (int jBase = 0; jBase < F; jBase += TJ) {
        // stage B tile: KD x TJ floats = 4096 float4, coalesced
        for (int l = tid; l < (KD * TJ) / 4; l += 256) {
            int k  = l >> 6;        // TJ/4 = 64 float4 per k-row
            int j4 = l & 63;
            ((float4*)&B_s[k][0])[j4] = crd4[k * (F / 4) + (jBase >> 2) + j4];
        }
        __syncthreads();

        float acc[4][4];
#pragma unroll
        for (int r = 0; r < 4; ++r)
#pragma unroll
            for (int c = 0; c < 4; ++c) acc[r][c] = 0.f;

        for (int k = 0; k < KD; ++k) {
            float4 a = *(const float4*)&A_s[k][ty * 4];   // broadcast within wave
            float4 b = *(const float4*)&B_s[k][tx * 4];
            acc[0][0] = fmaf(a.x, b.x, acc[0][0]);
            acc[0][1] = fmaf(a.x, b.y, acc[0][1]);
            acc[0][2] = fmaf(a.x, b.z, acc[0][2]);
            acc[0][3] = fmaf(a.x, b.w, acc[0][3]);
            acc[1][0] = fmaf(a.y, b.x, acc[1][0]);
            acc[1][1] = fmaf(a.y, b.y, acc[1][1]);
            acc[1][2] = fmaf(a.y, b.z, acc[1][2]);
            acc[1][3] = fmaf(a.y, b.w, acc[1][3]);
            acc[2][0] = fmaf(a.z, b.x, acc[2][0]);
            acc[2][1] = fmaf(a.z, b.y, acc[2][1]);
            acc[2][2] = fmaf(a.z, b.z, acc[2][2]);
            acc[2][3] = fmaf(a.z, b.w, acc[2][3]);
            acc[3][0] = fmaf(a.w, b.x, acc[3][0]);
            acc[3][1] = fmaf(a.w, b.y, acc[3][1]);
            acc[3][2] = fmaf(a.w, b.z, acc[3][2]);
            acc[3][3] = fmaf(a.w, b.w, acc[3][3]);
        }

        // top-8 update; c ascending => j ascending per thread, so strict '<'
        // insertion keeps earlier-j first among equal values (top_k tie rule)
#pragma unroll
        for (int c = 0; c < 4; ++c) {
            int   j   = jBase + tx * 4 + c;
            float sqj = sq[j];
#pragma unroll
            for (int r = 0; r < 4; ++r) {
                float d = (sqi[r] + sqj) - 2.f * acc[r][c];
                if (d < tv[r][NB - 1]) {
                    tv[r][NB - 1]  = d;
                    tix[r][NB - 1] = j;
#pragma unroll
                    for (int p = NB - 1; p > 0; --p) {
                        if (tv[r][p] < tv[r][p - 1]) {   // strict: equal keeps earlier j first
                            float fv = tv[r][p]; tv[r][p] = tv[r][p - 1]; tv[r][p - 1] = fv;
                            int   iv = tix[r][p]; tix[r][p] = tix[r][p - 1]; tix[r][p - 1] = iv;
                        }
                    }
                }
            }
        }
        __syncthreads();   // before next tile overwrites B_s (also covers merge reuse)
    }

    // ---- merge: per row, 64 threads x 8 candidates = 512, reuse B_s space ----
    float* mv = (float*)B_s;                         // [16][512] floats, 32 KB
    int*   mi = (int*)((char*)B_s + TI * 512 * 4);   // [16][512] ints,   32 KB
#pragma unroll
    for (int r = 0; r < 4; ++r)
#pragma unroll
        for (int s = 0; s < NB; ++s) {
            mv[(ty * 4 + r) * 512 + tx * NB + s] = tv[r][s];
            mi[(ty * 4 + r) * 512 + tx * NB + s] = tix[r][s];
        }
    __syncthreads();

    if (tid < TI) {
        const int row = tid;
        float* rv = &mv[row * 512];
        int*   ri = &mi[row * 512];
        for (int s = 0; s < NB; ++s) {
            float bestV = INFINITY;
            int   bestI = 0x7fffffff;
            int   bestP = 0;
            for (int q = 0; q < 512; ++q) {
                float v = rv[q];
                int   id = ri[q];
                if (v < bestV || (v == bestV && id < bestI)) {
                    bestV = v; bestI = id; bestP = q;
                }
            }
            rv[bestP] = INFINITY;   // exclude; each j is unique within a row
            knn[(rowBase + row) * NB + s] = bestI;
        }
    }
}

// ---------------------------------------------------------------------------
// Kernel 3: gather. Block handles one (b,c) row x one quarter of the g-range.
// Input row staged in LDS (32 KB); knn reads and out writes fully coalesced.
// flat_idx[g] = (g == 0) ? 0 : knn[g]   (covers both the f=0 special-case and
// the general f>=1 rows, since knn[0*8+g] == knn[g] for g in 1..7).
// ---------------------------------------------------------------------------
__global__ __launch_bounds__(256) void gather_kernel(const float* __restrict__ inp,
                                                     const int* __restrict__ knn,
                                                     float* __restrict__ out) {
    __shared__ float row[F];    // 32 KB
    const int bc    = blockIdx.x >> 2;   // 0..255  (b*4+c)
    const int chunk = blockIdx.x & 3;    // 0..3
    const int tid   = threadIdx.x;

    const float4* in4  = (const float4*)(inp + (size_t)bc * F);
    float4*       row4 = (float4*)row;
    for (int l = tid; l < F / 4; l += 256) row4[l] = in4[l];
    __syncthreads();

    const int GTOT  = F * NB;          // 65536
    const int gBase = chunk * (GTOT / 4);
    float* outp = out + (size_t)bc * GTOT + gBase;

    for (int i = 0; i < (GTOT / 4) / 256; ++i) {   // 64 iterations
        int g  = gBase + i * 256 + tid;
        int fi = (g == 0) ? 0 : knn[g];
        outp[i * 256 + tid] = row[fi];
    }
}

extern "C" void kernel_launch(void* const* d_in, const int* in_sizes, int n_in,
                              void* d_out, int out_size, void* d_ws, size_t ws_size,
                              hipStream_t stream) {
    const float* inp = (const float*)d_in[0];   // (64,4,8192,1) fp32
    const float* crd = (const float*)d_in[1];   // (64,1,8192)  fp32
    float* out = (float*)d_out;                 // (64,4,65536,1) fp32

    float* sq  = (float*)d_ws;                       // 8192 floats = 32 KB
    int*   knn = (int*)((char*)d_ws + 32768);        // 8192*8 ints = 256 KB

    sq_kernel<<<F / 256, 256, 0, stream>>>(crd, sq);
    knn_kernel<<<F / TI, 256, 0, stream>>>(crd, sq, knn);
    gather_kernel<<<256 * 4, 256, 0, stream>>>(inp, knn, out);
}

// Round 2
// 497.794 us; speedup vs baseline: 1.4603x; 1.4603x over previous
//
#include <hip/hip_runtime.h>

#define F    8192
#define KD   64     // coordinate dimensionality
#define NB   8      // neighbors
#define TI   16     // rows per workgroup (knn kernel)
#define TJ   256    // cols per LDS tile
#define RPT  8      // rows per thread
#define CPT  2      // cols per thread

// ---------------------------------------------------------------------------
// Kernel 1: squared norms. Same ascending-k fmaf chain as the dot product in
// knn_kernel so dot(i,i) == sq[i] bit-exact => d2[i][i] == 0 exactly.
// ---------------------------------------------------------------------------
__global__ __launch_bounds__(256) void sq_kernel(const float* __restrict__ crd,
                                                 float* __restrict__ sq) {
    int f = blockIdx.x * 256 + threadIdx.x;
    float acc = 0.f;
    for (int k = 0; k < KD; ++k) {
        float x = crd[k * F + f];
        acc = fmaf(x, x, acc);
    }
    sq[f] = acc;
}

// ---------------------------------------------------------------------------
// Kernel 2: fused distance + top-8.
// Block = 256 threads = 4 waves. wave = (wr, wc): wr picks 8 rows, wc picks a
// 128-col half of the 256-col LDS tile. Thread tile: 8 rows x 2 cols.
// A-operands are wave-uniform -> scalar loads from global (SGPRs, no LDS).
// B staged in LDS (64 KB). LDS pipe: 1 ds_read_b64 (4 cyc) per 32 VALU-cyc
// per wave -> 4 waves = 50% of LDS BW (was 100% with the 4x4 tile).
// Merge: per-wave shuffle-pop top-8 (no bank conflicts), then a two-pointer
// merge of the two col-half lists per row.
// ---------------------------------------------------------------------------
__global__ __launch_bounds__(256, 2) void knn_kernel(const float* __restrict__ crd,
                                                     const float* __restrict__ sq,
                                                     int* __restrict__ knn) {
    __shared__ float B_s[KD][TJ];        // 64 KB
    __shared__ float resV[TI][2][NB];    // 1 KB
    __shared__ int   resI[TI][2][NB];    // 1 KB

    const int tid  = threadIdx.x;
    const int wave = tid >> 6;
    const int tx   = tid & 63;
    const int wr   = wave & 1;           // row half
    const int wc   = wave >> 1;          // col half
    const int cBase = wc * 128 + tx * CPT;

    // wave-uniform row base, forced into SGPR so A loads scalarize
    const int rb = __builtin_amdgcn_readfirstlane(blockIdx.x * TI + wr * RPT);

    float sqi[RPT];
#pragma unroll
    for (int r = 0; r < RPT; ++r) sqi[r] = sq[rb + r];

    float tv[RPT][NB];
    int   tix[RPT][NB];
#pragma unroll
    for (int r = 0; r < RPT; ++r)
#pragma unroll
        for (int s = 0; s < NB; ++s) { tv[r][s] = INFINITY; tix[r][s] = 0x7fffffff; }

    const float4* crd4 = (const float4*)crd;

    for (int jBase = 0; jBase < F; jBase += TJ) {
        // stage B tile: 64x256 floats = 4096 float4, 16 per thread, coalesced
#pragma unroll
        for (int i = 0; i < 16; ++i) {
            int l  = tid + i * 256;
            int k  = l >> 6;          // 64 float4 per k-row
            int j4 = l & 63;
            ((float4*)&B_s[k][0])[j4] = crd4[k * (F / 4) + (jBase >> 2) + j4];
        }
        __syncthreads();

        float acc[RPT][CPT];
#pragma unroll
        for (int r = 0; r < RPT; ++r)
#pragma unroll
            for (int c = 0; c < CPT; ++c) acc[r][c] = 0.f;

#pragma unroll 8
        for (int k = 0; k < KD; ++k) {
            float2 b = *(const float2*)&B_s[k][cBase];
            const float* arow = crd + k * F + rb;   // scalar (SGPR) loads
#pragma unroll
            for (int r = 0; r < RPT; ++r) {
                float a = arow[r];
                acc[r][0] = fmaf(a, b.x, acc[r][0]);
                acc[r][1] = fmaf(a, b.y, acc[r][1]);
            }
        }

        // top-8 update, lexicographic (val, idx) tie-break
        float2 sqj = *(const float2*)&sq[jBase + cBase];
#pragma unroll
        for (int c = 0; c < CPT; ++c) {
            int   j  = jBase + cBase + c;
            float sj = c ? sqj.y : sqj.x;
#pragma unroll
            for (int r = 0; r < RPT; ++r) {
                float d = (sqi[r] + sj) - 2.f * acc[r][c];
                if (d < tv[r][NB - 1] ||
                    (d == tv[r][NB - 1] && j < tix[r][NB - 1])) {
                    tv[r][NB - 1]  = d;
                    tix[r][NB - 1] = j;
#pragma unroll
                    for (int p = NB - 1; p > 0; --p) {
                        bool sw = (tv[r][p] < tv[r][p - 1]) ||
                                  (tv[r][p] == tv[r][p - 1] && tix[r][p] < tix[r][p - 1]);
                        if (sw) {
                            float fv = tv[r][p]; tv[r][p] = tv[r][p - 1]; tv[r][p - 1] = fv;
                            int   iv = tix[r][p]; tix[r][p] = tix[r][p - 1]; tix[r][p - 1] = iv;
                        }
                    }
                }
            }
        }
        __syncthreads();   // before next tile overwrites B_s
    }

    // ---- wave-level merge: 8 rounds of 64-lane lexicographic min + pop ----
#pragma unroll
    for (int r = 0; r < RPT; ++r) {
#pragma unroll
        for (int s = 0; s < NB; ++s) {
            float bv = tv[r][0];
            int   bi = tix[r][0];
#pragma unroll
            for (int off = 32; off >= 1; off >>= 1) {
                float ov = __shfl_xor(bv, off, 64);
                int   oi = __shfl_xor(bi, off, 64);
                if (ov < bv || (ov == bv && oi < bi)) { bv = ov; bi = oi; }
            }
            // exactly one lane owns the winner ((val,idx) unique per row)
            if (tv[r][0] == bv && tix[r][0] == bi) {
#pragma unroll
                for (int p = 0; p < NB - 1; ++p) {
                    tv[r][p] = tv[r][p + 1]; tix[r][p] = tix[r][p + 1];
                }
                tv[r][NB - 1] = INFINITY; tix[r][NB - 1] = 0x7fffffff;
            }
            if (tx == 0) {
                resV[wr * RPT + r][wc][s] = bv;
                resI[wr * RPT + r][wc][s] = bi;
            }
        }
    }
    __syncthreads();

    // ---- final merge of the two sorted col-half lists per row ----
    if (tid < TI) {
        int p0 = 0, p1 = 0;
#pragma unroll
        for (int s = 0; s < NB; ++s) {
            float v0 = resV[tid][0][p0], v1 = resV[tid][1][p1];
            int   i0 = resI[tid][0][p0], i1 = resI[tid][1][p1];
            bool take0 = (v0 < v1) || (v0 == v1 && i0 < i1);
            knn[(blockIdx.x * TI + tid) * NB + s] = take0 ? i0 : i1;
            if (take0) ++p0; else ++p1;
        }
    }
}

// ---------------------------------------------------------------------------
// Kernel 3: gather. Block = one (b,c) row x one quarter of the g-range.
// Input row staged in LDS; knn reads and out writes fully coalesced.
// ---------------------------------------------------------------------------
__global__ __launch_bounds__(256) void gather_kernel(const float* __restrict__ inp,
                                                     const int* __restrict__ knn,
                                                     float* __restrict__ out) {
    __shared__ float row[F];    // 32 KB
    const int bc    = blockIdx.x >> 2;
    const int chunk = blockIdx.x & 3;
    const int tid   = threadIdx.x;

    const float4* in4  = (const float4*)(inp + (size_t)bc * F);
    float4*       row4 = (float4*)row;
    for (int l = tid; l < F / 4; l += 256) row4[l] = in4[l];
    __syncthreads();

    const int GTOT  = F * NB;          // 65536
    const int gBase = chunk * (GTOT / 4);
    float* outp = out + (size_t)bc * GTOT + gBase;

    for (int i = 0; i < (GTOT / 4) / 256; ++i) {   // 64 iterations
        int g  = gBase + i * 256 + tid;
        int fi = (g == 0) ? 0 : knn[g];
        outp[i * 256 + tid] = row[fi];
    }
}

extern "C" void kernel_launch(void* const* d_in, const int* in_sizes, int n_in,
                              void* d_out, int out_size, void* d_ws, size_t ws_size,
                              hipStream_t stream) {
    const float* inp = (const float*)d_in[0];   // (64,4,8192,1) fp32
    const float* crd = (const float*)d_in[1];   // (64,1,8192)  fp32
    float* out = (float*)d_out;                 // (64,4,65536,1) fp32

    float* sq  = (float*)d_ws;                       // 8192 floats
    int*   knn = (int*)((char*)d_ws + 32768);        // 8192*8 ints

    sq_kernel<<<F / 256, 256, 0, stream>>>(crd, sq);
    knn_kernel<<<F / TI, 256, 0, stream>>>(crd, sq, knn);
    gather_kernel<<<256 * 4, 256, 0, stream>>>(inp, knn, out);
}

// Round 3
// 397.987 us; speedup vs baseline: 1.8266x; 1.2508x over previous
//
#include <hip/hip_runtime.h>

#define F    8192
#define KD   64      // coordinate dimensionality
#define NB   8       // neighbors
#define TI   32      // rows per block
#define TJ   256     // cols per j-tile
#define RPT  8       // rows per thread (per wave)
#define NTILES (F / TJ)
#define CAP  64      // per-row candidate buffer capacity (per refresh interval)

typedef unsigned long long u64;

__device__ __forceinline__ u64 pack64(float d, int j) {
    // d >= 0 -> f32 bit pattern is order-preserving as u32; low 32 = index.
    // u64 ascending order == lexicographic (d, j) == jax top_k tie-break.
    return ((u64)__float_as_uint(d) << 32) | (unsigned)j;
}

// ---------------------------------------------------------------------------
// Kernel 1: squared norms. Same ascending-k fmaf chain as the dot product in
// knn_kernel so dot(i,i) == sq[i] bit-exact => d2[i][i] == 0 exactly.
// ---------------------------------------------------------------------------
__global__ __launch_bounds__(256) void sq_kernel(const float* __restrict__ crd,
                                                 float* __restrict__ sq) {
    int f = blockIdx.x * 256 + threadIdx.x;
    float acc = 0.f;
    for (int k = 0; k < KD; ++k) {
        float x = crd[k * F + f];
        acc = fmaf(x, x, acc);
    }
    sq[f] = acc;
}

// ---------------------------------------------------------------------------
// Kernel 2: fused distance + top-8, threshold/buffer selection.
// Block = 512 threads = 8 waves = (wr 0..3 row-group) x (wc 0..1 col-half).
// Thread tile: 8 rows (scalar A from global via SGPR) x 2 cols (LDS b64).
// Selection: tile 0 -> exact wave-level top-8 per row (shuffle-pop, u64).
// Tiles >=1 -> 1 float cmp vs per-row threshold; rare survivors appended to
// a per-row LDS buffer; periodic lane-per-row merges refresh the threshold.
// Register state for selection = 8 floats -> no spills (R2's 128-reg lists
// spilled to scratch; that was the 436us).
// ---------------------------------------------------------------------------
__global__ __launch_bounds__(512, 2) void knn_kernel(const float* __restrict__ crd,
                                                     const float* __restrict__ sq,
                                                     int* __restrict__ knn) {
    __shared__ float B_s[KD][TJ];         // 64 KB
    __shared__ u64   buf[TI][CAP + 1];    // 16.6 KB (pad -> 2-way banks, free)
    __shared__ u64   lst[TI][NB + 1];     // 2.3 KB
    __shared__ u64   stg[TI][17];         // 4.3 KB (16 used + pad)
    __shared__ int   cnt[TI];

    const int tid  = threadIdx.x;
    const int wave = tid >> 6;
    const int tx   = tid & 63;
    const int wr   = wave >> 1;           // 0..3: row group
    const int wc   = wave & 1;            // 0..1: col half
    const int rowBase = blockIdx.x * TI;
    const int rb   = __builtin_amdgcn_readfirstlane(rowBase + wr * RPT);
    const int cloc = wc * 128 + tx * 2;   // col within tile

    float sqi[RPT];
#pragma unroll
    for (int r = 0; r < RPT; ++r) sqi[r] = sq[rb + r];

    float td[RPT];                        // per-row threshold (current 8th-best d)

    const float4* crd4 = (const float4*)crd;

    for (int t = 0; t < NTILES; ++t) {
        // ---- stage B tile: 64x256 floats = 4096 float4 / 512 thr = 8 each ----
#pragma unroll
        for (int i = 0; i < 8; ++i) {
            int l  = tid + i * 512;
            int k  = l >> 6;              // TJ/4 = 64 float4 per k-row
            int j4 = l & 63;
            ((float4*)&B_s[k][0])[j4] = crd4[k * (F / 4) + t * (TJ / 4) + j4];
        }
        __syncthreads();

        // ---- GEMM micro-tile: 8 rows (scalar A) x 2 cols (LDS) ----
        float acc[RPT][2];
#pragma unroll
        for (int r = 0; r < RPT; ++r) { acc[r][0] = 0.f; acc[r][1] = 0.f; }

#pragma unroll 8
        for (int k = 0; k < KD; ++k) {
            float2 b = *(const float2*)&B_s[k][cloc];
            const float* arow = crd + k * F + rb;  // uniform -> s_load
#pragma unroll
            for (int r = 0; r < RPT; ++r) {
                float a = arow[r];
                acc[r][0] = fmaf(a, b.x, acc[r][0]);
                acc[r][1] = fmaf(a, b.y, acc[r][1]);
            }
        }

        const int j0 = t * TJ + cloc;
        float2 sj = *(const float2*)&sq[j0];

        if (t == 0) {
            // exact per-row top-8 of this wave's 128 cols via shuffle-pop
#pragma unroll
            for (int r = 0; r < RPT; ++r) {
                float d0 = fmaxf((sqi[r] + sj.x) - 2.f * acc[r][0], 0.f);
                float d1 = fmaxf((sqi[r] + sj.y) - 2.f * acc[r][1], 0.f);
                u64 c0 = pack64(d0, j0);
                u64 c1 = pack64(d1, j0 + 1);
                if (c1 < c0) { u64 tw = c0; c0 = c1; c1 = tw; }
                int taken = 0;
#pragma unroll
                for (int s = 0; s < NB; ++s) {
                    u64 cur = (taken == 0) ? c0 : ((taken == 1) ? c1 : ~0ULL);
                    unsigned hi = (unsigned)(cur >> 32), lo = (unsigned)cur;
#pragma unroll
                    for (int off = 32; off >= 1; off >>= 1) {
                        unsigned ohi = (unsigned)__shfl_xor((int)hi, off, 64);
                        unsigned olo = (unsigned)__shfl_xor((int)lo, off, 64);
                        if (ohi < hi || (ohi == hi && olo < lo)) { hi = ohi; lo = olo; }
                    }
                    u64 m = ((u64)hi << 32) | lo;
                    if (cur == m) ++taken;    // unique winner (packed values unique)
                    if (tx == 0) stg[wr * RPT + r][wc * NB + s] = m;
                }
            }
            __syncthreads();
            if (tid < TI) {
                // merge the two sorted 8-runs (col halves) -> lst
                int p0 = 0, p1 = 0;
#pragma unroll
                for (int s = 0; s < NB; ++s) {
                    u64 a = (p0 < NB) ? stg[tid][p0]      : ~0ULL;
                    u64 b = (p1 < NB) ? stg[tid][NB + p1] : ~0ULL;
                    if (a <= b) { lst[tid][s] = a; ++p0; }
                    else        { lst[tid][s] = b; ++p1; }
                }
                cnt[tid] = 0;
            }
            __syncthreads();
#pragma unroll
            for (int r = 0; r < RPT; ++r) {
                unsigned u = (unsigned)(lst[wr * RPT + r][NB - 1] >> 32);
                td[r] = __uint_as_float(__builtin_amdgcn_readfirstlane((int)u));
            }
        } else {
            // cheap guard: d <= thresh (superset of "could be in top-8",
            // ties resolved exactly in the merge via u64 lex order)
#pragma unroll
            for (int r = 0; r < RPT; ++r) {
                const int lr = wr * RPT + r;
                float d0 = fmaxf((sqi[r] + sj.x) - 2.f * acc[r][0], 0.f);
                float d1 = fmaxf((sqi[r] + sj.y) - 2.f * acc[r][1], 0.f);
                if (d0 <= td[r]) {
                    int pos = atomicAdd(&cnt[lr], 1);
                    if (pos < CAP) buf[lr][pos] = pack64(d0, j0);
                }
                if (d1 <= td[r]) {
                    int pos = atomicAdd(&cnt[lr], 1);
                    if (pos < CAP) buf[lr][pos] = pack64(d1, j0 + 1);
                }
            }
        }
        __syncthreads();    // B_s consumed + appends visible

        // ---- periodic refresh: fold buffer into lst, tighten threshold ----
        if (t == 1 || t == 2 || t == 4 || t == 8 || t == 16) {
            if (tid < TI) {
                u64 L[NB];
#pragma unroll
                for (int s = 0; s < NB; ++s) L[s] = lst[tid][s];
                int n = min(cnt[tid], CAP);
                for (int i = 0; i < n; ++i) {
                    u64 x = buf[tid][i];
                    if (x < L[NB - 1]) {
                        L[NB - 1] = x;
#pragma unroll
                        for (int p = NB - 1; p > 0; --p) {
                            if (L[p] < L[p - 1]) { u64 tw = L[p]; L[p] = L[p - 1]; L[p - 1] = tw; }
                        }
                    }
                }
#pragma unroll
                for (int s = 0; s < NB; ++s) lst[tid][s] = L[s];
                cnt[tid] = 0;
            }
            __syncthreads();
#pragma unroll
            for (int r = 0; r < RPT; ++r) {
                unsigned u = (unsigned)(lst[wr * RPT + r][NB - 1] >> 32);
                td[r] = __uint_as_float(__builtin_amdgcn_readfirstlane((int)u));
            }
        }
    }

    // ---- final merge + write ----
    if (tid < TI) {
        u64 L[NB];
#pragma unroll
        for (int s = 0; s < NB; ++s) L[s] = lst[tid][s];
        int n = min(cnt[tid], CAP);
        for (int i = 0; i < n; ++i) {
            u64 x = buf[tid][i];
            if (x < L[NB - 1]) {
                L[NB - 1] = x;
#pragma unroll
                for (int p = NB - 1; p > 0; --p) {
                    if (L[p] < L[p - 1]) { u64 tw = L[p]; L[p] = L[p - 1]; L[p - 1] = tw; }
                }
            }
        }
#pragma unroll
        for (int s = 0; s < NB; ++s)
            knn[(rowBase + tid) * NB + s] = (int)(L[s] & 0xffffffffu);
    }
}

// ---------------------------------------------------------------------------
// Kernel 3: gather. Block = one (b,c) row x one quarter of the g-range.
// Input row staged in LDS; knn reads and out writes fully coalesced.
// ---------------------------------------------------------------------------
__global__ __launch_bounds__(256) void gather_kernel(const float* __restrict__ inp,
                                                     const int* __restrict__ knn,
                                                     float* __restrict__ out) {
    __shared__ float row[F];    // 32 KB
    const int bc    = blockIdx.x >> 2;
    const int chunk = blockIdx.x & 3;
    const int tid   = threadIdx.x;

    const float4* in4  = (const float4*)(inp + (size_t)bc * F);
    float4*       row4 = (float4*)row;
    for (int l = tid; l < F / 4; l += 256) row4[l] = in4[l];
    __syncthreads();

    const int GTOT  = F * NB;          // 65536
    const int gBase = chunk * (GTOT / 4);
    float* outp = out + (size_t)bc * GTOT + gBase;

    for (int i = 0; i < (GTOT / 4) / 256; ++i) {   // 64 iterations
        int g  = gBase + i * 256 + tid;
        int fi = (g == 0) ? 0 : knn[g];
        outp[i * 256 + tid] = row[fi];
    }
}

extern "C" void kernel_launch(void* const* d_in, const int* in_sizes, int n_in,
                              void* d_out, int out_size, void* d_ws, size_t ws_size,
                              hipStream_t stream) {
    const float* inp = (const float*)d_in[0];   // (64,4,8192,1) fp32
    const float* crd = (const float*)d_in[1];   // (64,1,8192)  fp32
    float* out = (float*)d_out;                 // (64,4,65536,1) fp32

    float* sq  = (float*)d_ws;                       // 8192 floats
    int*   knn = (int*)((char*)d_ws + 32768);        // 8192*8 ints

    sq_kernel<<<F / 256, 256, 0, stream>>>(crd, sq);
    knn_kernel<<<F / TI, 512, 0, stream>>>(crd, sq, knn);
    gather_kernel<<<256 * 4, 256, 0, stream>>>(inp, knn, out);
}

// Round 4
// 293.483 us; speedup vs baseline: 2.4770x; 1.3561x over previous
//
#include <hip/hip_runtime.h>

#define F    8192
#define KD   64      // coordinate dimensionality
#define NB   8       // neighbors
#define TI   16      // rows per block
#define RPW  8       // rows per wave row-group
#define CPL  4       // cols per lane
#define SPAN 1024    // cols per pass (4 wave-stripes x 64 lanes x 4 cols)
#define NPASS (F / SPAN)   // 8
#define CAP  64      // per-row candidate buffer capacity per refresh interval

typedef unsigned long long u64;

__device__ __forceinline__ u64 pack64(float d, int j) {
    // d >= 0 -> f32 bits order-preserving as u32; low 32 = index.
    // u64 ascending == lexicographic (d, j) == jax top_k tie-break.
    return ((u64)__float_as_uint(d) << 32) | (unsigned)j;
}

// ---------------------------------------------------------------------------
// Kernel 1: squared norms. Same ascending-k fmaf chain as the dot product in
// knn_kernel so dot(i,i) == sq[i] bit-exact => d2[i][i] == 0 exactly.
// ---------------------------------------------------------------------------
__global__ __launch_bounds__(256) void sq_kernel(const float* __restrict__ crd,
                                                 float* __restrict__ sq) {
    int f = blockIdx.x * 256 + threadIdx.x;
    float acc = 0.f;
    for (int k = 0; k < KD; ++k) {
        float x = crd[k * F + f];
        acc = fmaf(x, x, acc);
    }
    sq[f] = acc;
}

// ---------------------------------------------------------------------------
// Kernel 2: fused distance + top-8, barrier-free main loop.
// Block = 512 thr = 8 waves = (wr 0..1: 8-row group) x (wc 0..3: 256-col
// stripe). Lane tile: 8 rows x 4 cols. A via scalar s_load (wave-uniform
// rows, scalar pipe — no VALU slots); B read straight from global (fully
// coalesced 1KB/wave/k, L2-resident: crd = 2MB < 4MB/XCD). No B LDS, no
// per-tile barriers — R3's 89KB LDS + 2 barriers/tile at 1 block/CU was the
// 75% stall. LDS here ~10KB -> 2 blocks/CU co-resident, waves free-run.
// Selection: pass 0 -> per-wave exact stripe top-8 (shuffle-pop on packed
// u64) appended to LDS buffer; passes 1..7 -> 1 cmp vs per-row threshold,
// rare survivors appended; refresh thresholds after passes 0,1,2,4.
// ---------------------------------------------------------------------------
__global__ __launch_bounds__(512, 4) void knn_kernel(const float* __restrict__ crd,
                                                     const float* __restrict__ sq,
                                                     int* __restrict__ knn) {
    __shared__ u64 buf[TI][CAP + 1];   // 8.3 KB (pad: fold reads conflict-free)
    __shared__ u64 lst[TI][NB + 1];    // 1.2 KB
    __shared__ int cnt[TI];

    const int tid  = threadIdx.x;
    const int wave = tid >> 6;
    const int tx   = tid & 63;
    const int wr   = wave >> 2;        // 0..1: row group
    const int wc   = wave & 3;         // 0..3: col stripe
    const int rowBase = blockIdx.x * TI;
    const int rb   = __builtin_amdgcn_readfirstlane(rowBase + wr * RPW);

    float sqi[RPW];                    // wave-uniform -> s_load, SGPRs
#pragma unroll
    for (int r = 0; r < RPW; ++r) sqi[r] = sq[rb + r];

    if (tid < TI) cnt[tid] = 0;
    __syncthreads();

    float td[RPW];                     // per-row threshold (8th-best so far)

    const float4* crd4 = (const float4*)crd;

    for (int p = 0; p < NPASS; ++p) {
        const int j0 = p * SPAN + wc * 256 + tx * CPL;

        float acc[RPW][CPL];
#pragma unroll
        for (int r = 0; r < RPW; ++r)
#pragma unroll
            for (int c = 0; c < CPL; ++c) acc[r][c] = 0.f;

#pragma unroll 8
        for (int k = 0; k < KD; ++k) {
            float4 b = crd4[k * (F / 4) + (j0 >> 2)];   // coalesced, L2-hit
            const float* arow = crd + k * F + rb;        // uniform -> s_load
#pragma unroll
            for (int r = 0; r < RPW; ++r) {
                float a = arow[r];
                acc[r][0] = fmaf(a, b.x, acc[r][0]);
                acc[r][1] = fmaf(a, b.y, acc[r][1]);
                acc[r][2] = fmaf(a, b.z, acc[r][2]);
                acc[r][3] = fmaf(a, b.w, acc[r][3]);
            }
        }

        float4 sj = *(const float4*)&sq[j0];

        if (p == 0) {
            // per-wave exact top-8 of this 256-col stripe, per row
#pragma unroll
            for (int r = 0; r < RPW; ++r) {
                u64 c0 = pack64(fmaxf((sqi[r] + sj.x) - 2.f * acc[r][0], 0.f), j0);
                u64 c1 = pack64(fmaxf((sqi[r] + sj.y) - 2.f * acc[r][1], 0.f), j0 + 1);
                u64 c2 = pack64(fmaxf((sqi[r] + sj.z) - 2.f * acc[r][2], 0.f), j0 + 2);
                u64 c3 = pack64(fmaxf((sqi[r] + sj.w) - 2.f * acc[r][3], 0.f), j0 + 3);
                // sort 4 in-lane (network)
                u64 t;
                if (c1 < c0) { t = c0; c0 = c1; c1 = t; }
                if (c3 < c2) { t = c2; c2 = c3; c3 = t; }
                if (c2 < c0) { t = c0; c0 = c2; c2 = t; }
                if (c3 < c1) { t = c1; c1 = c3; c3 = t; }
                if (c2 < c1) { t = c1; c1 = c2; c2 = t; }
                int taken = 0;
#pragma unroll
                for (int s = 0; s < NB; ++s) {
                    u64 cur = (taken == 0) ? c0 : (taken == 1) ? c1 :
                              (taken == 2) ? c2 : (taken == 3) ? c3 : ~0ULL;
                    u64 m = cur;
#pragma unroll
                    for (int off = 32; off >= 1; off >>= 1) {
                        u64 o = __shfl_xor(m, off, 64);
                        if (o < m) m = o;
                    }
                    if (cur == m) ++taken;   // unique winner (j distinct)
                    if (tx == 0) buf[wr * RPW + r][wc * NB + s] = m;
                }
            }
        } else {
            // cheap guard vs threshold; rare survivors appended
#pragma unroll
            for (int r = 0; r < RPW; ++r) {
                const int lr = wr * RPW + r;
                float d0 = fmaxf((sqi[r] + sj.x) - 2.f * acc[r][0], 0.f);
                float d1 = fmaxf((sqi[r] + sj.y) - 2.f * acc[r][1], 0.f);
                float d2 = fmaxf((sqi[r] + sj.z) - 2.f * acc[r][2], 0.f);
                float d3 = fmaxf((sqi[r] + sj.w) - 2.f * acc[r][3], 0.f);
                if (d0 <= td[r]) { int q = atomicAdd(&cnt[lr], 1); if (q < CAP) buf[lr][q] = pack64(d0, j0);     }
                if (d1 <= td[r]) { int q = atomicAdd(&cnt[lr], 1); if (q < CAP) buf[lr][q] = pack64(d1, j0 + 1); }
                if (d2 <= td[r]) { int q = atomicAdd(&cnt[lr], 1); if (q < CAP) buf[lr][q] = pack64(d2, j0 + 2); }
                if (d3 <= td[r]) { int q = atomicAdd(&cnt[lr], 1); if (q < CAP) buf[lr][q] = pack64(d3, j0 + 3); }
            }
        }

        // ---- threshold refresh: fold buffer into lst (exact, u64 lex) ----
        if (p == 0 || p == 1 || p == 2 || p == 4) {
            __syncthreads();
            if (tid < TI) {
                u64 L[NB];
                if (p == 0) {
#pragma unroll
                    for (int s = 0; s < NB; ++s) L[s] = ~0ULL;
                } else {
#pragma unroll
                    for (int s = 0; s < NB; ++s) L[s] = lst[tid][s];
                }
                int n = (p == 0) ? 4 * NB : min(cnt[tid], CAP);
                for (int i = 0; i < n; ++i) {
                    u64 x = buf[tid][i];
                    if (x < L[NB - 1]) {
                        L[NB - 1] = x;
#pragma unroll
                        for (int q = NB - 1; q > 0; --q)
                            if (L[q] < L[q - 1]) { u64 w = L[q]; L[q] = L[q - 1]; L[q - 1] = w; }
                    }
                }
#pragma unroll
                for (int s = 0; s < NB; ++s) lst[tid][s] = L[s];
                cnt[tid] = 0;
            }
            __syncthreads();
#pragma unroll
            for (int r = 0; r < RPW; ++r) {
                u64 v = lst[wr * RPW + r][NB - 1];     // broadcast read
                td[r] = __uint_as_float(__builtin_amdgcn_readfirstlane((int)(unsigned)(v >> 32)));
            }
        }
    }

    // ---- final fold + write ----
    __syncthreads();
    if (tid < TI) {
        u64 L[NB];
#pragma unroll
        for (int s = 0; s < NB; ++s) L[s] = lst[tid][s];
        int n = min(cnt[tid], CAP);
        for (int i = 0; i < n; ++i) {
            u64 x = buf[tid][i];
            if (x < L[NB - 1]) {
                L[NB - 1] = x;
#pragma unroll
                for (int q = NB - 1; q > 0; --q)
                    if (L[q] < L[q - 1]) { u64 w = L[q]; L[q] = L[q - 1]; L[q - 1] = w; }
            }
        }
#pragma unroll
        for (int s = 0; s < NB; ++s)
            knn[(rowBase + tid) * NB + s] = (int)(L[s] & 0xffffffffu);
    }
}

// ---------------------------------------------------------------------------
// Kernel 3: gather, 4x vectorized. Block = one (b,c) row x quarter g-range.
// int4 knn loads + 4 LDS reads + float4 stores, all coalesced.
// ---------------------------------------------------------------------------
__global__ __launch_bounds__(256) void gather_kernel(const float* __restrict__ inp,
                                                     const int* __restrict__ knn,
                                                     float* __restrict__ out) {
    __shared__ float row[F];    // 32 KB
    const int bc    = blockIdx.x >> 2;
    const int chunk = blockIdx.x & 3;
    const int tid   = threadIdx.x;

    const float4* in4  = (const float4*)(inp + (size_t)bc * F);
    float4*       row4 = (float4*)row;
    for (int l = tid; l < F / 4; l += 256) row4[l] = in4[l];
    __syncthreads();

    const int GTOT  = F * NB;              // 65536
    const int gBase = chunk * (GTOT / 4);  // multiple of 4
    const int4*  kn4 = (const int4*)(knn + gBase);
    float4*      ou4 = (float4*)(out + (size_t)bc * GTOT + gBase);

    for (int i = 0; i < (GTOT / 16) / 256; ++i) {   // 16 iterations
        int e = i * 256 + tid;
        int4 idx = kn4[e];
        if (gBase + e * 4 == 0) idx.x = 0;          // flat_idx[0] hardcoded 0
        float4 o;
        o.x = row[idx.x]; o.y = row[idx.y]; o.z = row[idx.z]; o.w = row[idx.w];
        ou4[e] = o;
    }
}

extern "C" void kernel_launch(void* const* d_in, const int* in_sizes, int n_in,
                              void* d_out, int out_size, void* d_ws, size_t ws_size,
                              hipStream_t stream) {
    const float* inp = (const float*)d_in[0];   // (64,4,8192,1) fp32
    const float* crd = (const float*)d_in[1];   // (64,1,8192)  fp32
    float* out = (float*)d_out;                 // (64,4,65536,1) fp32

    float* sq  = (float*)d_ws;                       // 8192 floats
    int*   knn = (int*)((char*)d_ws + 32768);        // 8192*8 ints

    sq_kernel<<<F / 256, 256, 0, stream>>>(crd, sq);
    knn_kernel<<<F / TI, 512, 0, stream>>>(crd, sq, knn);
    gather_kernel<<<256 * 4, 256, 0, stream>>>(inp, knn, out);
}

// Round 5
// 277.600 us; speedup vs baseline: 2.6187x; 1.0572x over previous
//
#include <hip/hip_runtime.h>

#define F    8192
#define KD   64      // coordinate dimensionality
#define NB   8       // neighbors
#define TI   16      // rows per block
#define RPW  8       // rows per wave row-group
#define CPL  4       // cols per lane
#define SPAN 1024    // cols per pass (4 wave-stripes x 64 lanes x 4 cols)
#define JSPLIT 2     // column halves (occupancy: grid = 512*JSPLIT blocks)
#define NPASS (F / SPAN / JSPLIT)   // 4 passes over this block's 4096 cols
#define CAP  64      // per-row candidate buffer capacity per refresh interval

typedef unsigned long long u64;

__device__ __forceinline__ u64 pack64(float d, int j) {
    // d >= 0 -> f32 bits order-preserving as u32; low 32 = index.
    // u64 ascending == lexicographic (d, j) == jax top_k tie-break.
    return ((u64)__float_as_uint(d) << 32) | (unsigned)j;
}

// ---------------------------------------------------------------------------
// Kernel 1: squared norms. Same ascending-k fmaf chain as the dot product in
// knn_kernel so dot(i,i) == sq[i] bit-exact => d2[i][i] == 0 exactly.
// ---------------------------------------------------------------------------
__global__ __launch_bounds__(256) void sq_kernel(const float* __restrict__ crd,
                                                 float* __restrict__ sq) {
    int f = blockIdx.x * 256 + threadIdx.x;
    float acc = 0.f;
    for (int k = 0; k < KD; ++k) {
        float x = crd[k * F + f];
        acc = fmaf(x, x, acc);
    }
    sq[f] = acc;
}

// ---------------------------------------------------------------------------
// Kernel 2: fused distance + top-8 over a (16-row x 4096-col) slab.
// grid = 1024 blocks (512 row-blocks x 2 col-halves) -> 4 blocks/CU,
// 32 waves/CU (R4 was grid-limited to 2 blocks/CU = 50% occupancy; that,
// not VALU, was the limiter: VALUBusy 37.7%).
// Block = 512 thr = 8 waves = (wr 0..1: 8-row group) x (wc 0..3: 256-col
// stripe). Lane tile: 8 rows (scalar A via s_load) x 4 cols (global float4,
// coalesced, L2-resident). Barrier-free main loop; threshold+buffer select.
// Each block writes exact top-8 (u64-packed) of its col-half to `part`;
// merge_kernel combines the two halves per row.
// ---------------------------------------------------------------------------
__global__ __launch_bounds__(512, 8) void knn_kernel(const float* __restrict__ crd,
                                                     const float* __restrict__ sq,
                                                     u64* __restrict__ part) {
    __shared__ u64 buf[TI][CAP + 1];   // 8.3 KB
    __shared__ u64 lst[TI][NB + 1];    // 1.2 KB
    __shared__ int cnt[TI];

    const int tid   = threadIdx.x;
    const int wave  = tid >> 6;
    const int tx    = tid & 63;
    const int wr    = wave >> 2;       // 0..1: row group
    const int wc    = wave & 3;        // 0..3: col stripe
    const int jhalf = blockIdx.x & (JSPLIT - 1);
    const int iblk  = blockIdx.x >> 1;
    const int rowBase = iblk * TI;
    const int jBase   = jhalf * (F / JSPLIT);
    const int rb    = __builtin_amdgcn_readfirstlane(rowBase + wr * RPW);

    float sqi[RPW];                    // wave-uniform -> s_load, SGPRs
#pragma unroll
    for (int r = 0; r < RPW; ++r) sqi[r] = sq[rb + r];

    if (tid < TI) cnt[tid] = 0;
    __syncthreads();

    float td[RPW];                     // per-row threshold (8th-best so far)

    const float4* crd4 = (const float4*)crd;

    for (int p = 0; p < NPASS; ++p) {
        const int j0 = jBase + p * SPAN + wc * 256 + tx * CPL;

        float acc[RPW][CPL];
#pragma unroll
        for (int r = 0; r < RPW; ++r)
#pragma unroll
            for (int c = 0; c < CPL; ++c) acc[r][c] = 0.f;

#pragma unroll 8
        for (int k = 0; k < KD; ++k) {
            float4 b = crd4[k * (F / 4) + (j0 >> 2)];   // coalesced, L2-hit
            const float* arow = crd + k * F + rb;        // uniform -> s_load
#pragma unroll
            for (int r = 0; r < RPW; ++r) {
                float a = arow[r];
                acc[r][0] = fmaf(a, b.x, acc[r][0]);
                acc[r][1] = fmaf(a, b.y, acc[r][1]);
                acc[r][2] = fmaf(a, b.z, acc[r][2]);
                acc[r][3] = fmaf(a, b.w, acc[r][3]);
            }
        }

        float4 sj = *(const float4*)&sq[j0];

        if (p == 0) {
            // per-wave exact top-8 of this 256-col stripe, per row
#pragma unroll
            for (int r = 0; r < RPW; ++r) {
                u64 c0 = pack64(fmaxf((sqi[r] + sj.x) - 2.f * acc[r][0], 0.f), j0);
                u64 c1 = pack64(fmaxf((sqi[r] + sj.y) - 2.f * acc[r][1], 0.f), j0 + 1);
                u64 c2 = pack64(fmaxf((sqi[r] + sj.z) - 2.f * acc[r][2], 0.f), j0 + 2);
                u64 c3 = pack64(fmaxf((sqi[r] + sj.w) - 2.f * acc[r][3], 0.f), j0 + 3);
                u64 t;
                if (c1 < c0) { t = c0; c0 = c1; c1 = t; }
                if (c3 < c2) { t = c2; c2 = c3; c3 = t; }
                if (c2 < c0) { t = c0; c0 = c2; c2 = t; }
                if (c3 < c1) { t = c1; c1 = c3; c3 = t; }
                if (c2 < c1) { t = c1; c1 = c2; c2 = t; }
                int taken = 0;
#pragma unroll
                for (int s = 0; s < NB; ++s) {
                    u64 cur = (taken == 0) ? c0 : (taken == 1) ? c1 :
                              (taken == 2) ? c2 : (taken == 3) ? c3 : ~0ULL;
                    u64 m = cur;
#pragma unroll
                    for (int off = 32; off >= 1; off >>= 1) {
                        u64 o = __shfl_xor(m, off, 64);
                        if (o < m) m = o;
                    }
                    if (cur == m) ++taken;   // unique winner (j distinct)
                    if (tx == 0) buf[wr * RPW + r][wc * NB + s] = m;
                }
            }
        } else {
            // cheap guard vs threshold; rare survivors appended
#pragma unroll
            for (int r = 0; r < RPW; ++r) {
                const int lr = wr * RPW + r;
                float d0 = fmaxf((sqi[r] + sj.x) - 2.f * acc[r][0], 0.f);
                float d1 = fmaxf((sqi[r] + sj.y) - 2.f * acc[r][1], 0.f);
                float d2 = fmaxf((sqi[r] + sj.z) - 2.f * acc[r][2], 0.f);
                float d3 = fmaxf((sqi[r] + sj.w) - 2.f * acc[r][3], 0.f);
                if (d0 <= td[r]) { int q = atomicAdd(&cnt[lr], 1); if (q < CAP) buf[lr][q] = pack64(d0, j0);     }
                if (d1 <= td[r]) { int q = atomicAdd(&cnt[lr], 1); if (q < CAP) buf[lr][q] = pack64(d1, j0 + 1); }
                if (d2 <= td[r]) { int q = atomicAdd(&cnt[lr], 1); if (q < CAP) buf[lr][q] = pack64(d2, j0 + 2); }
                if (d3 <= td[r]) { int q = atomicAdd(&cnt[lr], 1); if (q < CAP) buf[lr][q] = pack64(d3, j0 + 3); }
            }
        }

        // ---- threshold refresh: fold buffer into lst (exact, u64 lex) ----
        if (p <= 2) {
            __syncthreads();
            if (tid < TI) {
                u64 L[NB];
                if (p == 0) {
#pragma unroll
                    for (int s = 0; s < NB; ++s) L[s] = ~0ULL;
                } else {
#pragma unroll
                    for (int s = 0; s < NB; ++s) L[s] = lst[tid][s];
                }
                int n = (p == 0) ? 4 * NB : min(cnt[tid], CAP);
                for (int i = 0; i < n; ++i) {
                    u64 x = buf[tid][i];
                    if (x < L[NB - 1]) {
                        L[NB - 1] = x;
#pragma unroll
                        for (int q = NB - 1; q > 0; --q)
                            if (L[q] < L[q - 1]) { u64 w = L[q]; L[q] = L[q - 1]; L[q - 1] = w; }
                    }
                }
#pragma unroll
                for (int s = 0; s < NB; ++s) lst[tid][s] = L[s];
                cnt[tid] = 0;
            }
            __syncthreads();
#pragma unroll
            for (int r = 0; r < RPW; ++r) {
                u64 v = lst[wr * RPW + r][NB - 1];     // broadcast read
                td[r] = __uint_as_float(__builtin_amdgcn_readfirstlane((int)(unsigned)(v >> 32)));
            }
        }
    }

    // ---- final fold + write partial list ----
    __syncthreads();
    if (tid < TI) {
        u64 L[NB];
#pragma unroll
        for (int s = 0; s < NB; ++s) L[s] = lst[tid][s];
        int n = min(cnt[tid], CAP);
        for (int i = 0; i < n; ++i) {
            u64 x = buf[tid][i];
            if (x < L[NB - 1]) {
                L[NB - 1] = x;
#pragma unroll
                for (int q = NB - 1; q > 0; --q)
                    if (L[q] < L[q - 1]) { u64 w = L[q]; L[q] = L[q - 1]; L[q - 1] = w; }
            }
        }
#pragma unroll
        for (int s = 0; s < NB; ++s)
            part[((size_t)jhalf * F + rowBase + tid) * NB + s] = L[s];
    }
}

// ---------------------------------------------------------------------------
// Kernel 2b: merge the two sorted col-half lists per row (u64 lex = exact
// jax tie-break). One thread per row.
// ---------------------------------------------------------------------------
__global__ __launch_bounds__(256) void merge_kernel(const u64* __restrict__ part,
                                                    int* __restrict__ knn) {
    int row = blockIdx.x * 256 + threadIdx.x;
    const u64* a = part + (size_t)row * NB;
    const u64* b = part + ((size_t)F + row) * NB;
    int p0 = 0, p1 = 0;
#pragma unroll
    for (int s = 0; s < NB; ++s) {
        u64 va = a[p0], vb = b[p1];
        bool ta = va <= vb;
        knn[row * NB + s] = (int)((ta ? va : vb) & 0xffffffffu);
        if (ta) ++p0; else ++p1;
    }
}

// ---------------------------------------------------------------------------
// Kernel 3: gather. One block per (b,c) row; row staged in LDS once.
// int4 knn loads + 4 LDS reads + float4 stores, all coalesced.
// ---------------------------------------------------------------------------
__global__ __launch_bounds__(512) void gather_kernel(const float* __restrict__ inp,
                                                     const int* __restrict__ knn,
                                                     float* __restrict__ out) {
    __shared__ float row[F];    // 32 KB
    const int bc  = blockIdx.x;
    const int tid = threadIdx.x;

    const float4* in4  = (const float4*)(inp + (size_t)bc * F);
    float4*       row4 = (float4*)row;
#pragma unroll
    for (int i = 0; i < (F / 4) / 512; ++i) row4[i * 512 + tid] = in4[i * 512 + tid];
    __syncthreads();

    const int GTOT = F * NB;               // 65536
    const int4*  kn4 = (const int4*)knn;
    float4*      ou4 = (float4*)(out + (size_t)bc * GTOT);

    for (int i = 0; i < (GTOT / 4) / 512; ++i) {   // 32 iterations
        int e = i * 512 + tid;
        int4 idx = kn4[e];
        if (e == 0) idx.x = 0;             // flat_idx[0] hardcoded 0
        float4 o;
        o.x = row[idx.x]; o.y = row[idx.y]; o.z = row[idx.z]; o.w = row[idx.w];
        ou4[e] = o;
    }
}

extern "C" void kernel_launch(void* const* d_in, const int* in_sizes, int n_in,
                              void* d_out, int out_size, void* d_ws, size_t ws_size,
                              hipStream_t stream) {
    const float* inp = (const float*)d_in[0];   // (64,4,8192,1) fp32
    const float* crd = (const float*)d_in[1];   // (64,1,8192)  fp32
    float* out = (float*)d_out;                 // (64,4,65536,1) fp32

    float* sq   = (float*)d_ws;                        // 32 KB
    int*   knn  = (int*)((char*)d_ws + 32768);         // 256 KB
    u64*   part = (u64*)((char*)d_ws + 32768 + 262144);// 1 MB (2 x 8192 x 8 u64)

    sq_kernel<<<F / 256, 256, 0, stream>>>(crd, sq);
    knn_kernel<<<(F / TI) * JSPLIT, 512, 0, stream>>>(crd, sq, part);
    merge_kernel<<<F / 256, 256, 0, stream>>>(part, knn);
    gather_kernel<<<256, 512, 0, stream>>>(inp, knn, out);
}